// Round 1
// baseline (769.641 us; speedup 1.0000x reference)
//
#include <hip/hip_runtime.h>

#define N_NODES 100000
#define N_EDGES 1000000
#define D_FEAT  6
#define HIDDEN  300
#define HID_P   320          // padded hidden (multiple of 32)
#define MSG     100
#define OUTC    200          // 2*MSG
#define OUTC_P  208          // padded to multiple of 16
#define MT      64           // edges per block (1M / 64 = 15625 blocks exactly)
#define NT_H    (HID_P/16)   // 20 n-tiles for hidden
#define NT_M    (OUTC_P/16)  // 13 n-tiles for messages
#define KS_H    (HID_P/32)   // 10 k-steps of 32

typedef __bf16 bf16_t;
typedef __bf16 bf16x8 __attribute__((ext_vector_type(8)));
typedef float  floatx4 __attribute__((ext_vector_type(4)));

// LDS strides (elements). H_STRIDE=328: row stride 656B = 4-bank offset between
// rows -> 16 lanes' ds_read_b128 land 2-way per bank = free (m136). 656%16==0
// keeps every fragment load 16B-aligned. A1_STRIDE=40: 80B rows, 20-bank offset,
// also 2-way.
#define H_STRIDE  328
#define A1_STRIDE 40

// ---------------- weight pre-pack: fp32 -> bf16 in B-fragment order -------------
// Packed layout: chunks of 512 elements = one (n-tile, k-step) B-fragment for a
// whole wave: offset = ((nt*KS + ks)*64 + lane)*8 + j, element = W[k][n] with
// n = nt*16 + (lane&15), k = ks*32 + (lane>>4)*8 + j. Zero-padded outside real dims.
__global__ void prep_kernel(const float* __restrict__ W1, const float* __restrict__ W2,
                            const float* __restrict__ W3, bf16_t* __restrict__ W1P,
                            bf16_t* __restrict__ W2P, bf16_t* __restrict__ W3P) {
    const int n1 = NT_H * 512;          // W1P: 20 tiles, single k-step (K padded 12->32)
    const int n2 = NT_H * KS_H * 512;   // W2P
    const int n3 = NT_M * KS_H * 512;   // W3P
    const int total = n1 + n2 + n3;
    for (int id = blockIdx.x * blockDim.x + threadIdx.x; id < total;
         id += gridDim.x * blockDim.x) {
        if (id < n1) {
            int nt = id >> 9, rem = id & 511, lane = rem >> 3, j = rem & 7;
            int n = nt * 16 + (lane & 15), k = (lane >> 4) * 8 + j;
            float v = (n < HIDDEN && k < 2 * D_FEAT) ? W1[k * HIDDEN + n] : 0.f;
            W1P[id] = (bf16_t)v;
        } else if (id < n1 + n2) {
            int r = id - n1;
            int chunk = r >> 9, rem = r & 511, lane = rem >> 3, j = rem & 7;
            int ks = chunk % KS_H, nt = chunk / KS_H;
            int n = nt * 16 + (lane & 15), k = ks * 32 + (lane >> 4) * 8 + j;
            float v = (n < HIDDEN && k < HIDDEN) ? W2[k * HIDDEN + n] : 0.f;
            W2P[r] = (bf16_t)v;
        } else {
            int r = id - n1 - n2;
            int chunk = r >> 9, rem = r & 511, lane = rem >> 3, j = rem & 7;
            int ks = chunk % KS_H, nt = chunk / KS_H;
            int n = nt * 16 + (lane & 15), k = ks * 32 + (lane >> 4) * 8 + j;
            float v = (n < OUTC && k < HIDDEN) ? W3[k * OUTC + n] : 0.f;
            W3P[r] = (bf16_t)v;
        }
    }
}

// ---------------- base MAE loss: sum|y-t|/N_NODES ------------------------------
__global__ void base_loss_kernel(const float* __restrict__ y,
                                 const float* __restrict__ t,
                                 float* __restrict__ out) {
    float s = 0.f;
    for (int i = blockIdx.x * blockDim.x + threadIdx.x; i < N_NODES * 2;
         i += gridDim.x * blockDim.x)
        s += fabsf(y[i] - t[i]);
    #pragma unroll
    for (int off = 32; off; off >>= 1) s += __shfl_down(s, off);
    __shared__ float red[4];
    if ((threadIdx.x & 63) == 0) red[threadIdx.x >> 6] = s;
    __syncthreads();
    if (threadIdx.x == 0)
        atomicAdd(out, (red[0] + red[1] + red[2] + red[3]) * (1.0f / N_NODES));
}

// ---------------- fused edge MLP + KL ------------------------------------------
// 512 threads = 8 waves in a 2(M) x 4(N) grid. Each wave: 2 M-tiles (32 rows) x
// 5 N-tiles (80 cols) for GEMM1/2; GEMM3 n-tiles t = wn + 4j (t < 13).
// MFMA 16x16x32 bf16 layouts (m89/m120-verified):
//   A: m = lane&15, k = (lane>>4)*8 + j (8 contiguous k)
//   B: n = lane&15, k = (lane>>4)*8 + j
//   C/D: n = lane&15, m = (lane>>4)*4 + reg
__global__ __launch_bounds__(512, 2) void mlp_kernel(
    const float* __restrict__ x, const int* __restrict__ ei,
    const bf16_t* __restrict__ W1P, const bf16_t* __restrict__ W2P,
    const bf16_t* __restrict__ W3P,
    const float* __restrict__ b1, const float* __restrict__ b2,
    const float* __restrict__ b3, float* __restrict__ out) {
    __shared__ __align__(16) bf16_t A1[MT * A1_STRIDE];
    __shared__ __align__(16) bf16_t H1[MT * H_STRIDE];
    __shared__ __align__(16) bf16_t H2[MT * H_STRIDE];
    __shared__ float red[8];

    const int tid  = threadIdx.x;
    const int wave = tid >> 6, lane = tid & 63;
    const int quad = lane >> 4, l16 = lane & 15;
    const int wm = wave >> 2, wn = wave & 3;
    const long e0 = (long)blockIdx.x * MT;

    // zero A1 (cols >= 12 must be 0 for the padded K=32 of GEMM1)
    {
        uint* a32 = (uint*)A1;
        for (int i = tid; i < MT * A1_STRIDE / 2; i += 512) a32[i] = 0u;
    }
    __syncthreads();
    // gather: e = [x[src] | x[dst]] -> bf16 A-tile
    if (tid < 2 * MT) {
        int m = tid >> 1, side = tid & 1;
        int node = ei[(long)side * N_EDGES + e0 + m];
        const float* xr = x + (long)node * D_FEAT;
        bf16_t* dst = A1 + m * A1_STRIDE + side * D_FEAT;
        #pragma unroll
        for (int j = 0; j < D_FEAT; j++) dst[j] = (bf16_t)xr[j];
    }
    __syncthreads();

    // ---- GEMM1: h1 = relu(e @ W1 + b1), K=32 (one step) ----
    floatx4 acc1[2][5];
    {
        bf16x8 a[2];
        #pragma unroll
        for (int mi = 0; mi < 2; mi++)
            a[mi] = *(const bf16x8*)&A1[(wm * 32 + mi * 16 + l16) * A1_STRIDE + quad * 8];
        #pragma unroll
        for (int nt = 0; nt < 5; nt++) {
            int ntg = wn * 5 + nt;
            bf16x8 b = *(const bf16x8*)&W1P[(ntg * 64 + lane) * 8];
            #pragma unroll
            for (int mi = 0; mi < 2; mi++) {
                floatx4 z = {0.f, 0.f, 0.f, 0.f};
                acc1[mi][nt] = __builtin_amdgcn_mfma_f32_16x16x32_bf16(a[mi], b, z, 0, 0, 0);
            }
        }
    }
    #pragma unroll
    for (int nt = 0; nt < 5; nt++) {
        int n = wn * 80 + nt * 16 + l16;
        float bias = (n < HIDDEN) ? b1[n] : 0.f;
        #pragma unroll
        for (int mi = 0; mi < 2; mi++) {
            int mbase = wm * 32 + mi * 16 + quad * 4;
            #pragma unroll
            for (int r = 0; r < 4; r++) {
                float v = fmaxf(acc1[mi][nt][r] + bias, 0.f);
                H1[(mbase + r) * H_STRIDE + n] = (bf16_t)v;
            }
        }
    }
    __syncthreads();

    // ---- GEMM2: h2 = relu(h1 @ W2 + b2), K=320 ----
    floatx4 acc2[2][5];
    #pragma unroll
    for (int mi = 0; mi < 2; mi++)
        #pragma unroll
        for (int nt = 0; nt < 5; nt++) acc2[mi][nt] = (floatx4){0.f, 0.f, 0.f, 0.f};
    #pragma unroll 2
    for (int ks = 0; ks < KS_H; ks++) {
        bf16x8 a[2];
        #pragma unroll
        for (int mi = 0; mi < 2; mi++)
            a[mi] = *(const bf16x8*)&H1[(wm * 32 + mi * 16 + l16) * H_STRIDE + ks * 32 + quad * 8];
        #pragma unroll
        for (int nt = 0; nt < 5; nt++) {
            int ntg = wn * 5 + nt;
            bf16x8 b = *(const bf16x8*)&W2P[((ntg * KS_H + ks) * 64 + lane) * 8];
            #pragma unroll
            for (int mi = 0; mi < 2; mi++)
                acc2[mi][nt] = __builtin_amdgcn_mfma_f32_16x16x32_bf16(a[mi], b, acc2[mi][nt], 0, 0, 0);
        }
    }
    #pragma unroll
    for (int nt = 0; nt < 5; nt++) {
        int n = wn * 80 + nt * 16 + l16;
        float bias = (n < HIDDEN) ? b2[n] : 0.f;
        #pragma unroll
        for (int mi = 0; mi < 2; mi++) {
            int mbase = wm * 32 + mi * 16 + quad * 4;
            #pragma unroll
            for (int r = 0; r < 4; r++) {
                float v = fmaxf(acc2[mi][nt][r] + bias, 0.f);
                H2[(mbase + r) * H_STRIDE + n] = (bf16_t)v;
            }
        }
    }
    __syncthreads();

    // ---- GEMM3: messages = h2 @ W3 + b3, then KL in-register ----
    floatx4 acc3[2][4];
    #pragma unroll
    for (int mi = 0; mi < 2; mi++)
        #pragma unroll
        for (int j = 0; j < 4; j++) acc3[mi][j] = (floatx4){0.f, 0.f, 0.f, 0.f};
    #pragma unroll 2
    for (int ks = 0; ks < KS_H; ks++) {
        bf16x8 a[2];
        #pragma unroll
        for (int mi = 0; mi < 2; mi++)
            a[mi] = *(const bf16x8*)&H2[(wm * 32 + mi * 16 + l16) * H_STRIDE + ks * 32 + quad * 8];
        #pragma unroll
        for (int j = 0; j < 4; j++) {
            int ntg = wn + 4 * j;
            if (ntg < NT_M) {
                bf16x8 b = *(const bf16x8*)&W3P[((ntg * KS_H + ks) * 64 + lane) * 8];
                #pragma unroll
                for (int mi = 0; mi < 2; mi++)
                    acc3[mi][j] = __builtin_amdgcn_mfma_f32_16x16x32_bf16(a[mi], b, acc3[mi][j], 0, 0, 0);
            }
        }
    }
    float s = 0.f;
    #pragma unroll
    for (int j = 0; j < 4; j++) {
        int ntg = wn + 4 * j;
        if (ntg < NT_M) {
            int n = ntg * 16 + l16;
            if (n < OUTC) {
                float bias = b3[n];
                #pragma unroll
                for (int mi = 0; mi < 2; mi++)
                    #pragma unroll
                    for (int r = 0; r < 4; r++) {
                        float v = acc3[mi][j][r] + bias;
                        if (n < MSG) s += 0.5f * v * v;               // mu^2 term
                        else         s += 0.5f * (__expf(v) - v - 1.f); // exp(lv)-lv-1
                    }
            }
        }
    }
    #pragma unroll
    for (int off = 32; off; off >>= 1) s += __shfl_down(s, off);
    if (lane == 0) red[wave] = s;
    __syncthreads();
    if (tid == 0) {
        float t2 = 0.f;
        #pragma unroll
        for (int w = 0; w < 8; w++) t2 += red[w];
        atomicAdd(out, t2 * (1.0f / N_EDGES));
    }
}

extern "C" void kernel_launch(void* const* d_in, const int* in_sizes, int n_in,
                              void* d_out, int out_size, void* d_ws, size_t ws_size,
                              hipStream_t stream) {
    const float* x      = (const float*)d_in[0];
    const int*   ei     = (const int*)d_in[1];
    const float* y      = (const float*)d_in[2];
    const float* target = (const float*)d_in[3];
    const float* W1     = (const float*)d_in[4];
    const float* b1     = (const float*)d_in[5];
    const float* W2     = (const float*)d_in[6];
    const float* b2     = (const float*)d_in[7];
    const float* W3     = (const float*)d_in[8];
    const float* b3     = (const float*)d_in[9];
    float* out = (float*)d_out;

    bf16_t* W1P = (bf16_t*)d_ws;                 // 10240 el
    bf16_t* W2P = W1P + NT_H * 512;              // 102400 el
    bf16_t* W3P = W2P + NT_H * KS_H * 512;       // 66560 el  (total 358400 B)

    hipMemsetAsync(d_out, 0, sizeof(float), stream);
    prep_kernel<<<700, 256, 0, stream>>>(W1, W2, W3, W1P, W2P, W3P);
    base_loss_kernel<<<200, 256, 0, stream>>>(y, target, out);
    mlp_kernel<<<N_EDGES / MT, 512, 0, stream>>>(x, ei, W1P, W2P, W3P, b1, b2, b3, out);
}

// Round 2
// 516.401 us; speedup vs baseline: 1.4904x; 1.4904x over previous
//
#include <hip/hip_runtime.h>

#define N_NODES 100000
#define N_EDGES 1000000
#define D_FEAT  6
#define HIDDEN  300
#define HID_P   320          // padded hidden (multiple of 32)
#define MSG     100
#define OUTC    200          // 2*MSG
#define OUTC_P  208          // padded to multiple of 16
#define MT      64           // edges per block (1M / 64 = 15625 blocks exactly)
#define NT_H    (HID_P/16)   // 20 n-tiles for hidden
#define NT_M    (OUTC_P/16)  // 13 n-tiles for messages
#define KS_H    (HID_P/32)   // 10 k-steps of 32

typedef __bf16 bf16_t;
typedef __bf16 bf16x8 __attribute__((ext_vector_type(8)));
typedef float  floatx4 __attribute__((ext_vector_type(4)));

// LDS strides (elements). H_STRIDE=328: row stride 656B = 4-bank offset between
// rows -> 16 lanes' ds_read_b128 land 2-way per bank = free (m136). 656%16==0
// keeps every fragment load 16B-aligned. A1_STRIDE=40: 80B rows, 20-bank offset,
// also 2-way.
#define H_STRIDE  328
#define A1_STRIDE 40

// ---------------- weight pre-pack: fp32 -> bf16 in B-fragment order -------------
// Packed layout: chunks of 512 elements = one (n-tile, k-step) B-fragment for a
// whole wave: offset = ((nt*KS + ks)*64 + lane)*8 + j, element = W[k][n] with
// n = nt*16 + (lane&15), k = ks*32 + (lane>>4)*8 + j. Zero-padded outside real dims.
__global__ void prep_kernel(const float* __restrict__ W1, const float* __restrict__ W2,
                            const float* __restrict__ W3, bf16_t* __restrict__ W1P,
                            bf16_t* __restrict__ W2P, bf16_t* __restrict__ W3P) {
    const int n1 = NT_H * 512;          // W1P: 20 tiles, single k-step (K padded 12->32)
    const int n2 = NT_H * KS_H * 512;   // W2P
    const int n3 = NT_M * KS_H * 512;   // W3P
    const int total = n1 + n2 + n3;
    for (int id = blockIdx.x * blockDim.x + threadIdx.x; id < total;
         id += gridDim.x * blockDim.x) {
        if (id < n1) {
            int nt = id >> 9, rem = id & 511, lane = rem >> 3, j = rem & 7;
            int n = nt * 16 + (lane & 15), k = (lane >> 4) * 8 + j;
            float v = (n < HIDDEN && k < 2 * D_FEAT) ? W1[k * HIDDEN + n] : 0.f;
            W1P[id] = (bf16_t)v;
        } else if (id < n1 + n2) {
            int r = id - n1;
            int chunk = r >> 9, rem = r & 511, lane = rem >> 3, j = rem & 7;
            int ks = chunk % KS_H, nt = chunk / KS_H;
            int n = nt * 16 + (lane & 15), k = ks * 32 + (lane >> 4) * 8 + j;
            float v = (n < HIDDEN && k < HIDDEN) ? W2[k * HIDDEN + n] : 0.f;
            W2P[r] = (bf16_t)v;
        } else {
            int r = id - n1 - n2;
            int chunk = r >> 9, rem = r & 511, lane = rem >> 3, j = rem & 7;
            int ks = chunk % KS_H, nt = chunk / KS_H;
            int n = nt * 16 + (lane & 15), k = ks * 32 + (lane >> 4) * 8 + j;
            float v = (n < OUTC && k < HIDDEN) ? W3[k * OUTC + n] : 0.f;
            W3P[r] = (bf16_t)v;
        }
    }
}

// ---------------- base MAE loss: sum|y-t|/N_NODES ------------------------------
__global__ void base_loss_kernel(const float* __restrict__ y,
                                 const float* __restrict__ t,
                                 float* __restrict__ out) {
    float s = 0.f;
    for (int i = blockIdx.x * blockDim.x + threadIdx.x; i < N_NODES * 2;
         i += gridDim.x * blockDim.x)
        s += fabsf(y[i] - t[i]);
    #pragma unroll
    for (int off = 32; off; off >>= 1) s += __shfl_down(s, off);
    __shared__ float red[4];
    if ((threadIdx.x & 63) == 0) red[threadIdx.x >> 6] = s;
    __syncthreads();
    if (threadIdx.x == 0)
        atomicAdd(out, (red[0] + red[1] + red[2] + red[3]) * (1.0f / N_NODES));
}

// ---------------- fused edge MLP + KL ------------------------------------------
// 512 threads = 8 waves in a 2(M) x 4(N) grid. Each wave: 2 M-tiles (32 rows) x
// 5 N-tiles (80 cols) for GEMM1/2; GEMM3 n-tiles t = wn + 4j (t < 13).
// MFMA 16x16x32 bf16 layouts (m89/m120-verified):
//   A: m = lane&15, k = (lane>>4)*8 + j (8 contiguous k)
//   B: n = lane&15, k = (lane>>4)*8 + j
//   C/D: n = lane&15, m = (lane>>4)*4 + reg
// H buffer is SHARED between h1 and h2 (GEMM2 reads all of H before its
// epilogue overwrites it; extra barrier enforces) -> LDS 47.1 KB -> 3 blocks/CU.
// __launch_bounds__(512,6): 6 waves/SIMD needs VGPR<=85 (pool ~512/SIMD).
__global__ __launch_bounds__(512, 6) void mlp_kernel(
    const float* __restrict__ x, const int* __restrict__ ei,
    const bf16_t* __restrict__ W1P, const bf16_t* __restrict__ W2P,
    const bf16_t* __restrict__ W3P,
    const float* __restrict__ b1, const float* __restrict__ b2,
    const float* __restrict__ b3, float* __restrict__ out) {
    __shared__ __align__(16) bf16_t A1[MT * A1_STRIDE];
    __shared__ __align__(16) bf16_t H[MT * H_STRIDE];   // h1, then reused for h2
    __shared__ float red[8];

    const int tid  = threadIdx.x;
    const int wave = tid >> 6, lane = tid & 63;
    const int quad = lane >> 4, l16 = lane & 15;
    const int wm = wave >> 2, wn = wave & 3;
    const long e0 = (long)blockIdx.x * MT;

    // zero A1 (cols >= 12 must be 0 for the padded K=32 of GEMM1)
    {
        uint* a32 = (uint*)A1;
        for (int i = tid; i < MT * A1_STRIDE / 2; i += 512) a32[i] = 0u;
    }
    __syncthreads();
    // gather: e = [x[src] | x[dst]] -> bf16 A-tile
    if (tid < 2 * MT) {
        int m = tid >> 1, side = tid & 1;
        int node = ei[(long)side * N_EDGES + e0 + m];
        const float* xr = x + (long)node * D_FEAT;
        bf16_t* dst = A1 + m * A1_STRIDE + side * D_FEAT;
        #pragma unroll
        for (int j = 0; j < D_FEAT; j++) dst[j] = (bf16_t)xr[j];
    }
    __syncthreads();

    // ---- GEMM1: h1 = relu(e @ W1 + b1), K=32 (one step) ----
    floatx4 acc1[2][5];
    {
        bf16x8 a[2];
        #pragma unroll
        for (int mi = 0; mi < 2; mi++)
            a[mi] = *(const bf16x8*)&A1[(wm * 32 + mi * 16 + l16) * A1_STRIDE + quad * 8];
        #pragma unroll
        for (int nt = 0; nt < 5; nt++) {
            int ntg = wn * 5 + nt;
            bf16x8 b = *(const bf16x8*)&W1P[(ntg * 64 + lane) * 8];
            #pragma unroll
            for (int mi = 0; mi < 2; mi++) {
                floatx4 z = {0.f, 0.f, 0.f, 0.f};
                acc1[mi][nt] = __builtin_amdgcn_mfma_f32_16x16x32_bf16(a[mi], b, z, 0, 0, 0);
            }
        }
    }
    #pragma unroll
    for (int nt = 0; nt < 5; nt++) {
        int n = wn * 80 + nt * 16 + l16;
        float bias = (n < HIDDEN) ? b1[n] : 0.f;
        #pragma unroll
        for (int mi = 0; mi < 2; mi++) {
            int mbase = wm * 32 + mi * 16 + quad * 4;
            #pragma unroll
            for (int r = 0; r < 4; r++) {
                float v = fmaxf(acc1[mi][nt][r] + bias, 0.f);
                H[(mbase + r) * H_STRIDE + n] = (bf16_t)v;
            }
        }
    }
    __syncthreads();

    // ---- GEMM2: h2 = relu(h1 @ W2 + b2), K=320 ----
    floatx4 acc2[2][5];
    #pragma unroll
    for (int mi = 0; mi < 2; mi++)
        #pragma unroll
        for (int nt = 0; nt < 5; nt++) acc2[mi][nt] = (floatx4){0.f, 0.f, 0.f, 0.f};
    #pragma unroll 2
    for (int ks = 0; ks < KS_H; ks++) {
        bf16x8 a[2];
        #pragma unroll
        for (int mi = 0; mi < 2; mi++)
            a[mi] = *(const bf16x8*)&H[(wm * 32 + mi * 16 + l16) * H_STRIDE + ks * 32 + quad * 8];
        #pragma unroll
        for (int nt = 0; nt < 5; nt++) {
            int ntg = wn * 5 + nt;
            bf16x8 b = *(const bf16x8*)&W2P[((ntg * KS_H + ks) * 64 + lane) * 8];
            #pragma unroll
            for (int mi = 0; mi < 2; mi++)
                acc2[mi][nt] = __builtin_amdgcn_mfma_f32_16x16x32_bf16(a[mi], b, acc2[mi][nt], 0, 0, 0);
        }
    }
    __syncthreads();   // all H(h1) reads done before overwrite
    #pragma unroll
    for (int nt = 0; nt < 5; nt++) {
        int n = wn * 80 + nt * 16 + l16;
        float bias = (n < HIDDEN) ? b2[n] : 0.f;
        #pragma unroll
        for (int mi = 0; mi < 2; mi++) {
            int mbase = wm * 32 + mi * 16 + quad * 4;
            #pragma unroll
            for (int r = 0; r < 4; r++) {
                float v = fmaxf(acc2[mi][nt][r] + bias, 0.f);
                H[(mbase + r) * H_STRIDE + n] = (bf16_t)v;
            }
        }
    }
    __syncthreads();

    // ---- GEMM3: messages = h2 @ W3 + b3, then KL in-register ----
    floatx4 acc3[2][4];
    #pragma unroll
    for (int mi = 0; mi < 2; mi++)
        #pragma unroll
        for (int j = 0; j < 4; j++) acc3[mi][j] = (floatx4){0.f, 0.f, 0.f, 0.f};
    #pragma unroll 2
    for (int ks = 0; ks < KS_H; ks++) {
        bf16x8 a[2];
        #pragma unroll
        for (int mi = 0; mi < 2; mi++)
            a[mi] = *(const bf16x8*)&H[(wm * 32 + mi * 16 + l16) * H_STRIDE + ks * 32 + quad * 8];
        #pragma unroll
        for (int j = 0; j < 4; j++) {
            int ntg = wn + 4 * j;
            if (ntg < NT_M) {
                bf16x8 b = *(const bf16x8*)&W3P[((ntg * KS_H + ks) * 64 + lane) * 8];
                #pragma unroll
                for (int mi = 0; mi < 2; mi++)
                    acc3[mi][j] = __builtin_amdgcn_mfma_f32_16x16x32_bf16(a[mi], b, acc3[mi][j], 0, 0, 0);
            }
        }
    }
    float s = 0.f;
    #pragma unroll
    for (int j = 0; j < 4; j++) {
        int ntg = wn + 4 * j;
        if (ntg < NT_M) {
            int n = ntg * 16 + l16;
            if (n < OUTC) {
                float bias = b3[n];
                #pragma unroll
                for (int mi = 0; mi < 2; mi++)
                    #pragma unroll
                    for (int r = 0; r < 4; r++) {
                        float v = acc3[mi][j][r] + bias;
                        if (n < MSG) s += 0.5f * v * v;               // mu^2 term
                        else         s += 0.5f * (__expf(v) - v - 1.f); // exp(lv)-lv-1
                    }
            }
        }
    }
    #pragma unroll
    for (int off = 32; off; off >>= 1) s += __shfl_down(s, off);
    if (lane == 0) red[wave] = s;
    __syncthreads();
    if (tid == 0) {
        float t2 = 0.f;
        #pragma unroll
        for (int w = 0; w < 8; w++) t2 += red[w];
        atomicAdd(out, t2 * (1.0f / N_EDGES));
    }
}

extern "C" void kernel_launch(void* const* d_in, const int* in_sizes, int n_in,
                              void* d_out, int out_size, void* d_ws, size_t ws_size,
                              hipStream_t stream) {
    const float* x      = (const float*)d_in[0];
    const int*   ei     = (const int*)d_in[1];
    const float* y      = (const float*)d_in[2];
    const float* target = (const float*)d_in[3];
    const float* W1     = (const float*)d_in[4];
    const float* b1     = (const float*)d_in[5];
    const float* W2     = (const float*)d_in[6];
    const float* b2     = (const float*)d_in[7];
    const float* W3     = (const float*)d_in[8];
    const float* b3     = (const float*)d_in[9];
    float* out = (float*)d_out;

    bf16_t* W1P = (bf16_t*)d_ws;                 // 10240 el
    bf16_t* W2P = W1P + NT_H * 512;              // 102400 el
    bf16_t* W3P = W2P + NT_H * KS_H * 512;       // 66560 el  (total 358400 B)

    hipMemsetAsync(d_out, 0, sizeof(float), stream);
    prep_kernel<<<700, 256, 0, stream>>>(W1, W2, W3, W1P, W2P, W3P);
    base_loss_kernel<<<200, 256, 0, stream>>>(y, target, out);
    mlp_kernel<<<N_EDGES / MT, 512, 0, stream>>>(x, ei, W1P, W2P, W3P, b1, b2, b3, out);
}

// Round 3
// 490.423 us; speedup vs baseline: 1.5693x; 1.0530x over previous
//
#include <hip/hip_runtime.h>

#define N_NODES 100000
#define N_EDGES 1000000
#define D_FEAT  6
#define HIDDEN  300
#define HID_P   320          // padded hidden (multiple of 32)
#define MSG     100
#define OUTC    200          // 2*MSG
#define OUTC_P  208          // padded to multiple of 16
#define MT      64           // edges per block (1M / 64 = 15625 blocks exactly)
#define NT_H    (HID_P/16)   // 20 n-tiles for hidden
#define NT_M    (OUTC_P/16)  // 13 n-tiles for messages
#define KS_H    (HID_P/32)   // 10 k-steps of 32

typedef __bf16 bf16_t;
typedef __bf16 bf16x8 __attribute__((ext_vector_type(8)));
typedef float  floatx4 __attribute__((ext_vector_type(4)));

// LDS strides (elements). H_STRIDE=328: row stride 656B -> 4-bank offset between
// rows, 2-way b128 aliasing = free (m136). A1_STRIDE=40.
#define H_STRIDE  328
#define A1_STRIDE 40

// ---------------- prep (weight pack) + base MAE loss, merged --------------------
// Blocks [0, PREP_BLOCKS): fp32 -> bf16 B-fragment pack.
// Blocks [PREP_BLOCKS, PREP_BLOCKS+LOSS_BLOCKS): sum|y-t|/N_NODES.
// B-frag layout: chunk of 512 el = one (nt,ks) fragment: el = ((..)*64+lane)*8+j,
// element = W[k][n], n = nt*16+(lane&15), k = ks*32+(lane>>4)*8+j, zero-padded.
#define PREP_BLOCKS 700
#define LOSS_BLOCKS 200
__global__ void prep_kernel(const float* __restrict__ W1, const float* __restrict__ W2,
                            const float* __restrict__ W3, bf16_t* __restrict__ W1P,
                            bf16_t* __restrict__ W2P, bf16_t* __restrict__ W3P,
                            const float* __restrict__ y, const float* __restrict__ t,
                            float* __restrict__ out) {
    if (blockIdx.x >= PREP_BLOCKS) {
        float s = 0.f;
        for (int i = (blockIdx.x - PREP_BLOCKS) * blockDim.x + threadIdx.x;
             i < N_NODES * 2; i += LOSS_BLOCKS * blockDim.x)
            s += fabsf(y[i] - t[i]);
        #pragma unroll
        for (int off = 32; off; off >>= 1) s += __shfl_down(s, off);
        __shared__ float red[4];
        if ((threadIdx.x & 63) == 0) red[threadIdx.x >> 6] = s;
        __syncthreads();
        if (threadIdx.x == 0)
            atomicAdd(out, (red[0] + red[1] + red[2] + red[3]) * (1.0f / N_NODES));
        return;
    }
    const int n1 = NT_H * 512;          // W1P: 20 tiles, single k-step (K 12->32)
    const int n2 = NT_H * KS_H * 512;   // W2P
    const int n3 = NT_M * KS_H * 512;   // W3P
    const int total = n1 + n2 + n3;
    for (int id = blockIdx.x * blockDim.x + threadIdx.x; id < total;
         id += PREP_BLOCKS * blockDim.x) {
        if (id < n1) {
            int nt = id >> 9, rem = id & 511, lane = rem >> 3, j = rem & 7;
            int n = nt * 16 + (lane & 15), k = (lane >> 4) * 8 + j;
            float v = (n < HIDDEN && k < 2 * D_FEAT) ? W1[k * HIDDEN + n] : 0.f;
            W1P[id] = (bf16_t)v;
        } else if (id < n1 + n2) {
            int r = id - n1;
            int chunk = r >> 9, rem = r & 511, lane = rem >> 3, j = rem & 7;
            int ks = chunk % KS_H, nt = chunk / KS_H;
            int n = nt * 16 + (lane & 15), k = ks * 32 + (lane >> 4) * 8 + j;
            float v = (n < HIDDEN && k < HIDDEN) ? W2[k * HIDDEN + n] : 0.f;
            W2P[r] = (bf16_t)v;
        } else {
            int r = id - n1 - n2;
            int chunk = r >> 9, rem = r & 511, lane = rem >> 3, j = rem & 7;
            int ks = chunk % KS_H, nt = chunk / KS_H;
            int n = nt * 16 + (lane & 15), k = ks * 32 + (lane >> 4) * 8 + j;
            float v = (n < OUTC && k < HIDDEN) ? W3[k * OUTC + n] : 0.f;
            W3P[r] = (bf16_t)v;
        }
    }
}

// ---------------- fused edge MLP + KL ------------------------------------------
// 512 threads = 8 waves, 1(M) x 8(N): every wave owns all 4 M-tiles (mi=4),
// N-slices: GEMM1/2 nt = wn + 8t (t < cnt_h: 3 for wn<4 else 2);
// GEMM3 nt = wn + 5t (t < cnt_m: 2 for wn>=3 else 1). mi=4 halves B-frag
// L2 traffic per MFMA vs the R2 2x4 arrangement.
// MFMA 16x16x32 bf16 layouts (verified R1, absmax 0):
//   A: m = lane&15, k = (lane>>4)*8 + j; B: n = lane&15, k = (lane>>4)*8 + j
//   C/D: n = lane&15, m = (lane>>4)*4 + reg
// H shared between h1/h2 (barrier before overwrite) -> 47.1 KB -> 3 blocks/CU.
__global__ __launch_bounds__(512, 6) void mlp_kernel(
    const float* __restrict__ x, const int* __restrict__ ei,
    const bf16_t* __restrict__ W1P, const bf16_t* __restrict__ W2P,
    const bf16_t* __restrict__ W3P,
    const float* __restrict__ b1, const float* __restrict__ b2,
    const float* __restrict__ b3, float* __restrict__ out) {
    __shared__ __align__(16) bf16_t A1[MT * A1_STRIDE];
    __shared__ __align__(16) bf16_t H[MT * H_STRIDE];   // h1, then reused for h2
    __shared__ float red[8];

    const int tid  = threadIdx.x;
    const int wave = tid >> 6, lane = tid & 63;
    const int quad = lane >> 4, l16 = lane & 15;
    const int wn = wave;
    const int cnt_h = (wn < 4) ? 3 : 2;
    const int cnt_m = (wn >= 3) ? 2 : 1;
    const long e0 = (long)blockIdx.x * MT;

    // zero A1 (cols >= 12 must be 0 for the padded K=32 of GEMM1)
    {
        uint* a32 = (uint*)A1;
        for (int i = tid; i < MT * A1_STRIDE / 2; i += 512) a32[i] = 0u;
    }
    __syncthreads();
    // gather: e = [x[src] | x[dst]] -> bf16 A-tile
    if (tid < 2 * MT) {
        int m = tid >> 1, side = tid & 1;
        int node = ei[(long)side * N_EDGES + e0 + m];
        const float* xr = x + (long)node * D_FEAT;
        bf16_t* dst = A1 + m * A1_STRIDE + side * D_FEAT;
        #pragma unroll
        for (int j = 0; j < D_FEAT; j++) dst[j] = (bf16_t)xr[j];
    }
    __syncthreads();

    // ---- GEMM1: h1 = relu(e @ W1 + b1), K=32 (one step) ----
    floatx4 acc1[3][4];
    {
        bf16x8 a[4];
        #pragma unroll
        for (int mi = 0; mi < 4; mi++)
            a[mi] = *(const bf16x8*)&A1[(mi * 16 + l16) * A1_STRIDE + quad * 8];
        #pragma unroll
        for (int t = 0; t < 3; t++) {
            if (t < cnt_h) {
                int ntg = wn + 8 * t;
                bf16x8 b = *(const bf16x8*)&W1P[(ntg * 64 + lane) * 8];
                #pragma unroll
                for (int mi = 0; mi < 4; mi++) {
                    floatx4 z = {0.f, 0.f, 0.f, 0.f};
                    acc1[t][mi] = __builtin_amdgcn_mfma_f32_16x16x32_bf16(a[mi], b, z, 0, 0, 0);
                }
            }
        }
    }
    #pragma unroll
    for (int t = 0; t < 3; t++) {
        if (t < cnt_h) {
            int n = (wn + 8 * t) * 16 + l16;
            float bias = (n < HIDDEN) ? b1[n] : 0.f;
            #pragma unroll
            for (int mi = 0; mi < 4; mi++) {
                int mbase = mi * 16 + quad * 4;
                #pragma unroll
                for (int r = 0; r < 4; r++) {
                    float v = fmaxf(acc1[t][mi][r] + bias, 0.f);
                    H[(mbase + r) * H_STRIDE + n] = (bf16_t)v;
                }
            }
        }
    }
    __syncthreads();

    // ---- GEMM2: h2 = relu(h1 @ W2 + b2), K=320 ----
    floatx4 acc2[3][4];
    #pragma unroll
    for (int t = 0; t < 3; t++)
        #pragma unroll
        for (int mi = 0; mi < 4; mi++) acc2[t][mi] = (floatx4){0.f, 0.f, 0.f, 0.f};
    #pragma unroll 2
    for (int ks = 0; ks < KS_H; ks++) {
        bf16x8 a[4];
        #pragma unroll
        for (int mi = 0; mi < 4; mi++)
            a[mi] = *(const bf16x8*)&H[(mi * 16 + l16) * H_STRIDE + ks * 32 + quad * 8];
        #pragma unroll
        for (int t = 0; t < 3; t++) {
            if (t < cnt_h) {
                int ntg = wn + 8 * t;
                bf16x8 b = *(const bf16x8*)&W2P[((ntg * KS_H + ks) * 64 + lane) * 8];
                #pragma unroll
                for (int mi = 0; mi < 4; mi++)
                    acc2[t][mi] = __builtin_amdgcn_mfma_f32_16x16x32_bf16(a[mi], b, acc2[t][mi], 0, 0, 0);
            }
        }
    }
    __syncthreads();   // all H(h1) reads done before overwrite
    #pragma unroll
    for (int t = 0; t < 3; t++) {
        if (t < cnt_h) {
            int n = (wn + 8 * t) * 16 + l16;
            float bias = (n < HIDDEN) ? b2[n] : 0.f;
            #pragma unroll
            for (int mi = 0; mi < 4; mi++) {
                int mbase = mi * 16 + quad * 4;
                #pragma unroll
                for (int r = 0; r < 4; r++) {
                    float v = fmaxf(acc2[t][mi][r] + bias, 0.f);
                    H[(mbase + r) * H_STRIDE + n] = (bf16_t)v;
                }
            }
        }
    }
    __syncthreads();

    // ---- GEMM3: messages = h2 @ W3 + b3, then KL in-register ----
    floatx4 acc3[2][4];
    #pragma unroll
    for (int t = 0; t < 2; t++)
        #pragma unroll
        for (int mi = 0; mi < 4; mi++) acc3[t][mi] = (floatx4){0.f, 0.f, 0.f, 0.f};
    #pragma unroll 2
    for (int ks = 0; ks < KS_H; ks++) {
        bf16x8 a[4];
        #pragma unroll
        for (int mi = 0; mi < 4; mi++)
            a[mi] = *(const bf16x8*)&H[(mi * 16 + l16) * H_STRIDE + ks * 32 + quad * 8];
        #pragma unroll
        for (int t = 0; t < 2; t++) {
            if (t < cnt_m) {
                int ntg = wn + 5 * t;
                bf16x8 b = *(const bf16x8*)&W3P[((ntg * KS_H + ks) * 64 + lane) * 8];
                #pragma unroll
                for (int mi = 0; mi < 4; mi++)
                    acc3[t][mi] = __builtin_amdgcn_mfma_f32_16x16x32_bf16(a[mi], b, acc3[t][mi], 0, 0, 0);
            }
        }
    }
    float s = 0.f;
    #pragma unroll
    for (int t = 0; t < 2; t++) {
        if (t < cnt_m) {
            int n = (wn + 5 * t) * 16 + l16;
            if (n < OUTC) {
                float bias = b3[n];
                #pragma unroll
                for (int mi = 0; mi < 4; mi++)
                    #pragma unroll
                    for (int r = 0; r < 4; r++) {
                        float v = acc3[t][mi][r] + bias;
                        if (n < MSG) s += 0.5f * v * v;               // mu^2 term
                        else         s += 0.5f * (__expf(v) - v - 1.f); // exp(lv)-lv-1
                    }
            }
        }
    }
    #pragma unroll
    for (int off = 32; off; off >>= 1) s += __shfl_down(s, off);
    if (lane == 0) red[wave] = s;
    __syncthreads();
    if (tid == 0) {
        float t2 = 0.f;
        #pragma unroll
        for (int w = 0; w < 8; w++) t2 += red[w];
        atomicAdd(out, t2 * (1.0f / N_EDGES));
    }
}

extern "C" void kernel_launch(void* const* d_in, const int* in_sizes, int n_in,
                              void* d_out, int out_size, void* d_ws, size_t ws_size,
                              hipStream_t stream) {
    const float* x      = (const float*)d_in[0];
    const int*   ei     = (const int*)d_in[1];
    const float* y      = (const float*)d_in[2];
    const float* target = (const float*)d_in[3];
    const float* W1     = (const float*)d_in[4];
    const float* b1     = (const float*)d_in[5];
    const float* W2     = (const float*)d_in[6];
    const float* b2     = (const float*)d_in[7];
    const float* W3     = (const float*)d_in[8];
    const float* b3     = (const float*)d_in[9];
    float* out = (float*)d_out;

    bf16_t* W1P = (bf16_t*)d_ws;                 // 10240 el
    bf16_t* W2P = W1P + NT_H * 512;              // 102400 el
    bf16_t* W3P = W2P + NT_H * KS_H * 512;       // 66560 el  (total 358400 B)

    hipMemsetAsync(d_out, 0, sizeof(float), stream);
    prep_kernel<<<PREP_BLOCKS + LOSS_BLOCKS, 256, 0, stream>>>(
        W1, W2, W3, W1P, W2P, W3P, y, target, out);
    mlp_kernel<<<N_EDGES / MT, 512, 0, stream>>>(x, ei, W1P, W2P, W3P, b1, b2, b3, out);
}

// Round 4
// 458.788 us; speedup vs baseline: 1.6776x; 1.0690x over previous
//
#include <hip/hip_runtime.h>

#define N_NODES 100000
#define N_EDGES 1000000
#define D_FEAT  6
#define HIDDEN  300
#define HID_P   320          // padded hidden (multiple of 32)
#define MSG     100
#define OUTC    200          // 2*MSG
#define OUTC_P  208
#define MT      64           // edges per block
#define NT_H    (HID_P/16)   // 20 feature tiles for hidden layers
#define NT_M    (OUTC_P/16)  // 13 feature tiles for messages
#define KS_H    (HID_P/32)   // 10 k-steps of 32

typedef __bf16 bf16_t;
typedef __bf16 bf16x8 __attribute__((ext_vector_type(8)));
typedef __bf16 bf16x4 __attribute__((ext_vector_type(4)));
typedef float  floatx4 __attribute__((ext_vector_type(4)));

// ---------------- prep (weight pack) + base MAE loss, merged --------------------
// B-frag order pack (doubles as A-frag order under operand swap — same index map):
// chunk of 512 el = one (ft,ks) fragment: el = ((ft*KS+ks)*64+lane)*8+j,
// element = W[k][n], n = ft*16+(lane&15), k = ks*32+(lane>>4)*8+j, zero-padded.
#define PREP_BLOCKS 700
#define LOSS_BLOCKS 200
__global__ void prep_kernel(const float* __restrict__ W1, const float* __restrict__ W2,
                            const float* __restrict__ W3, bf16_t* __restrict__ W1P,
                            bf16_t* __restrict__ W2P, bf16_t* __restrict__ W3P,
                            const float* __restrict__ y, const float* __restrict__ t,
                            float* __restrict__ out) {
    if (blockIdx.x >= PREP_BLOCKS) {
        float s = 0.f;
        for (int i = (blockIdx.x - PREP_BLOCKS) * blockDim.x + threadIdx.x;
             i < N_NODES * 2; i += LOSS_BLOCKS * blockDim.x)
            s += fabsf(y[i] - t[i]);
        #pragma unroll
        for (int off = 32; off; off >>= 1) s += __shfl_down(s, off);
        __shared__ float red[4];
        if ((threadIdx.x & 63) == 0) red[threadIdx.x >> 6] = s;
        __syncthreads();
        if (threadIdx.x == 0)
            atomicAdd(out, (red[0] + red[1] + red[2] + red[3]) * (1.0f / N_NODES));
        return;
    }
    const int n1 = NT_H * 512;
    const int n2 = NT_H * KS_H * 512;
    const int n3 = NT_M * KS_H * 512;
    const int total = n1 + n2 + n3;
    for (int id = blockIdx.x * blockDim.x + threadIdx.x; id < total;
         id += PREP_BLOCKS * blockDim.x) {
        if (id < n1) {
            int nt = id >> 9, rem = id & 511, lane = rem >> 3, j = rem & 7;
            int n = nt * 16 + (lane & 15), k = (lane >> 4) * 8 + j;
            float v = (n < HIDDEN && k < 2 * D_FEAT) ? W1[k * HIDDEN + n] : 0.f;
            W1P[id] = (bf16_t)v;
        } else if (id < n1 + n2) {
            int r = id - n1;
            int chunk = r >> 9, rem = r & 511, lane = rem >> 3, j = rem & 7;
            int ks = chunk % KS_H, nt = chunk / KS_H;
            int n = nt * 16 + (lane & 15), k = ks * 32 + (lane >> 4) * 8 + j;
            float v = (n < HIDDEN && k < HIDDEN) ? W2[k * HIDDEN + n] : 0.f;
            W2P[r] = (bf16_t)v;
        } else {
            int r = id - n1 - n2;
            int chunk = r >> 9, rem = r & 511, lane = rem >> 3, j = rem & 7;
            int ks = chunk % KS_H, nt = chunk / KS_H;
            int n = nt * 16 + (lane & 15), k = ks * 32 + (lane >> 4) * 8 + j;
            float v = (n < OUTC && k < HIDDEN) ? W3[k * OUTC + n] : 0.f;
            W3P[r] = (bf16_t)v;
        }
    }
}

// ---------------- fused edge MLP + KL ------------------------------------------
// OPERAND SWAP: D = mfma(A=W_frag, B=H_frag) -> D rows (quad*4+reg) = 4 consecutive
// FEATURES, cols (lane&15) = edges. H lives in LDS in exact B-fragment order
// Hf[e][ks][lane][8] -> every read is a wave-contiguous 1KB ds_read_b128
// (conflict-free), every epilogue lane-write is one ds_write_b64 (2-way = free).
// 8 waves: wave w owns feature-tiles f = w+8t (3 for w<4 else 2) for GEMM1/2;
// GEMM3: f = w (+ w+5 for w>=3); every wave covers all 4 edge-tiles.
// Layouts (verified R1-R3, absmax 0): A: m=lane&15, k=(lane>>4)*8+j;
// B: n=lane&15, k=(lane>>4)*8+j; C/D: n=lane&15, m=(lane>>4)*4+reg.
__global__ __launch_bounds__(512, 6) void mlp_kernel(
    const float* __restrict__ x, const int* __restrict__ ei,
    const bf16_t* __restrict__ W1P, const bf16_t* __restrict__ W2P,
    const bf16_t* __restrict__ W3P,
    const float* __restrict__ b1, const float* __restrict__ b2,
    const float* __restrict__ b3, float* __restrict__ out) {
    __shared__ __align__(16) bf16_t A1f[4 * 64 * 8];          // 4 KB, frag order
    __shared__ __align__(16) bf16_t Hf[4 * KS_H * 64 * 8];    // 40 KB, frag order
    __shared__ float red[8];

    const int tid  = threadIdx.x;
    const int w    = tid >> 6, lane = tid & 63;
    const int q    = lane >> 4, l16 = lane & 15;
    const int cnt_h = (w < 4) ? 3 : 2;
    const int cnt_m = (w >= 3) ? 2 : 1;
    const long e0 = (long)blockIdx.x * MT;

    // zero A1f (k >= 12 must be 0 for GEMM1's padded K=32)
    *(ulong*)&A1f[tid * 4] = 0ul;
    __syncthreads();
    // gather: edge features -> A1f fragment order: elem(lane',j) =
    // feat k of edge (et*16 + (lane'&15)), k = (lane'>>4)*8 + j
    if (tid < 2 * MT) {
        int m = tid >> 1, side = tid & 1;
        int node = ei[(long)side * N_EDGES + e0 + m];
        const float* xr = x + (long)node * D_FEAT;
        int et = m >> 4, ml = m & 15;
        #pragma unroll
        for (int c = 0; c < D_FEAT; c++) {
            int k = side * D_FEAT + c;
            int lp = ml + 16 * (k >> 3);
            A1f[(et * 64 + lp) * 8 + (k & 7)] = (bf16_t)xr[c];
        }
    }
    __syncthreads();

    // ---- GEMM1: h1 = relu(e @ W1 + b1), K=32 (one step) ----
    floatx4 acc1[3][4];
    {
        bf16x8 hb[4];
        #pragma unroll
        for (int e = 0; e < 4; e++)
            hb[e] = *(const bf16x8*)&A1f[(e * 64 + lane) * 8];
        #pragma unroll
        for (int t = 0; t < 3; t++) {
            if (t < cnt_h) {
                bf16x8 wf = *(const bf16x8*)&W1P[((w + 8 * t) * 64 + lane) * 8];
                #pragma unroll
                for (int e = 0; e < 4; e++) {
                    floatx4 z = {0.f, 0.f, 0.f, 0.f};
                    acc1[t][e] = __builtin_amdgcn_mfma_f32_16x16x32_bf16(wf, hb[e], z, 0, 0, 0);
                }
            }
        }
    }
    #pragma unroll
    for (int t = 0; t < 3; t++) {
        if (t < cnt_h) {
            int n0 = (w + 8 * t) * 16 + 4 * q;           // 4 consecutive features
            floatx4 bv = (n0 < HIDDEN) ? *(const floatx4*)&b1[n0]
                                       : (floatx4){0.f, 0.f, 0.f, 0.f};
            int ks = n0 >> 5, lp = l16 + 16 * ((n0 >> 3) & 3), j0 = n0 & 7;
            #pragma unroll
            for (int e = 0; e < 4; e++) {
                bf16x4 pk;
                #pragma unroll
                for (int r = 0; r < 4; r++)
                    pk[r] = (bf16_t)fmaxf(acc1[t][e][r] + bv[r], 0.f);
                *(bf16x4*)&Hf[((e * KS_H + ks) * 64 + lp) * 8 + j0] = pk;
            }
        }
    }
    __syncthreads();

    // ---- GEMM2: h2 = relu(h1 @ W2 + b2), K=320 ----
    floatx4 acc2[3][4];
    #pragma unroll
    for (int t = 0; t < 3; t++)
        #pragma unroll
        for (int e = 0; e < 4; e++) acc2[t][e] = (floatx4){0.f, 0.f, 0.f, 0.f};
    #pragma unroll 2
    for (int ks = 0; ks < KS_H; ks++) {
        bf16x8 hb[4];
        #pragma unroll
        for (int e = 0; e < 4; e++)
            hb[e] = *(const bf16x8*)&Hf[((e * KS_H + ks) * 64 + lane) * 8];
        #pragma unroll
        for (int t = 0; t < 3; t++) {
            if (t < cnt_h) {
                bf16x8 wf = *(const bf16x8*)&W2P[(((w + 8 * t) * KS_H + ks) * 64 + lane) * 8];
                #pragma unroll
                for (int e = 0; e < 4; e++)
                    acc2[t][e] = __builtin_amdgcn_mfma_f32_16x16x32_bf16(wf, hb[e], acc2[t][e], 0, 0, 0);
            }
        }
    }
    __syncthreads();   // all Hf(h1) reads done before overwrite
    #pragma unroll
    for (int t = 0; t < 3; t++) {
        if (t < cnt_h) {
            int n0 = (w + 8 * t) * 16 + 4 * q;
            floatx4 bv = (n0 < HIDDEN) ? *(const floatx4*)&b2[n0]
                                       : (floatx4){0.f, 0.f, 0.f, 0.f};
            int ks = n0 >> 5, lp = l16 + 16 * ((n0 >> 3) & 3), j0 = n0 & 7;
            #pragma unroll
            for (int e = 0; e < 4; e++) {
                bf16x4 pk;
                #pragma unroll
                for (int r = 0; r < 4; r++)
                    pk[r] = (bf16_t)fmaxf(acc2[t][e][r] + bv[r], 0.f);
                *(bf16x4*)&Hf[((e * KS_H + ks) * 64 + lp) * 8 + j0] = pk;
            }
        }
    }
    __syncthreads();

    // ---- GEMM3: messages = h2 @ W3 + b3, KL in-register ----
    floatx4 acc3[2][4];
    #pragma unroll
    for (int t = 0; t < 2; t++)
        #pragma unroll
        for (int e = 0; e < 4; e++) acc3[t][e] = (floatx4){0.f, 0.f, 0.f, 0.f};
    #pragma unroll 2
    for (int ks = 0; ks < KS_H; ks++) {
        bf16x8 hb[4];
        #pragma unroll
        for (int e = 0; e < 4; e++)
            hb[e] = *(const bf16x8*)&Hf[((e * KS_H + ks) * 64 + lane) * 8];
        #pragma unroll
        for (int t = 0; t < 2; t++) {
            if (t < cnt_m) {
                bf16x8 wf = *(const bf16x8*)&W3P[(((w + 5 * t) * KS_H + ks) * 64 + lane) * 8];
                #pragma unroll
                for (int e = 0; e < 4; e++)
                    acc3[t][e] = __builtin_amdgcn_mfma_f32_16x16x32_bf16(wf, hb[e], acc3[t][e], 0, 0, 0);
            }
        }
    }
    float s = 0.f;
    #pragma unroll
    for (int t = 0; t < 2; t++) {
        if (t < cnt_m) {
            int n0 = (w + 5 * t) * 16 + 4 * q;           // 4 consecutive features
            if (n0 < OUTC) {                              // runs never straddle 100/200
                floatx4 bv = *(const floatx4*)&b3[n0];
                bool is_mu = (n0 < MSG);
                #pragma unroll
                for (int e = 0; e < 4; e++)
                    #pragma unroll
                    for (int r = 0; r < 4; r++) {
                        float v = acc3[t][e][r] + bv[r];
                        if (is_mu) s += 0.5f * v * v;
                        else       s += 0.5f * (__expf(v) - v - 1.f);
                    }
            }
        }
    }
    #pragma unroll
    for (int off = 32; off; off >>= 1) s += __shfl_down(s, off);
    if (lane == 0) red[w] = s;
    __syncthreads();
    if (tid == 0) {
        float t2 = 0.f;
        #pragma unroll
        for (int i = 0; i < 8; i++) t2 += red[i];
        atomicAdd(out, t2 * (1.0f / N_EDGES));
    }
}

extern "C" void kernel_launch(void* const* d_in, const int* in_sizes, int n_in,
                              void* d_out, int out_size, void* d_ws, size_t ws_size,
                              hipStream_t stream) {
    const float* x      = (const float*)d_in[0];
    const int*   ei     = (const int*)d_in[1];
    const float* y      = (const float*)d_in[2];
    const float* target = (const float*)d_in[3];
    const float* W1     = (const float*)d_in[4];
    const float* b1     = (const float*)d_in[5];
    const float* W2     = (const float*)d_in[6];
    const float* b2     = (const float*)d_in[7];
    const float* W3     = (const float*)d_in[8];
    const float* b3     = (const float*)d_in[9];
    float* out = (float*)d_out;

    bf16_t* W1P = (bf16_t*)d_ws;
    bf16_t* W2P = W1P + NT_H * 512;
    bf16_t* W3P = W2P + NT_H * KS_H * 512;

    hipMemsetAsync(d_out, 0, sizeof(float), stream);
    prep_kernel<<<PREP_BLOCKS + LOSS_BLOCKS, 256, 0, stream>>>(
        W1, W2, W3, W1P, W2P, W3P, y, target, out);
    mlp_kernel<<<N_EDGES / MT, 512, 0, stream>>>(x, ei, W1P, W2P, W3P, b1, b2, b3, out);
}